// Round 18
// baseline (189.814 us; speedup 1.0000x reference)
//
#include <hip/hip_runtime.h>
#include <hip/hip_bf16.h>

typedef unsigned short u16;
typedef unsigned int u32;
typedef __attribute__((ext_vector_type(8))) short short8;
typedef __attribute__((ext_vector_type(4))) float f32x4;
typedef __attribute__((ext_vector_type(4))) int i32x4;

#define NN 8192
#define FIN 512
#define FOUT 128
#define NEG 0.2f
#define L2E 1.44269504088896340736f
#define EXP2(x) __builtin_amdgcn_exp2f(x)
#define LOG2(x) __builtin_amdgcn_logf(x)

__device__ __forceinline__ u16 f2bf(float f) {
  u32 u = __builtin_bit_cast(u32, f);
  u32 r = (u + 0x7fffu + ((u >> 16) & 1u)) >> 16;
  return (u16)r;
}

// K1: h = x @ w. 16-row tiles -> 512 blocks (2/CU, 8 waves/CU). Emits s,t
// scores and hb in MFMA-native coalesced layout:
// hb[kgrp][nblk][kg][nlo][e] = bf16(h[kgrp*32 + kg*8 + e][nblk*16 + nlo]).
__global__ __launch_bounds__(256) void k_h(const float* __restrict__ x,
                                           const float* __restrict__ w,
                                           const float* __restrict__ av,
                                           u16* __restrict__ hb,
                                           float* __restrict__ sg,
                                           float* __restrict__ tgo) {
  __shared__ float xs[16][68];
  __shared__ float ws_[64][128];
  __shared__ u16 ht[16][130];
  const int t = threadIdx.x;
  const int r0 = blockIdx.x * 16;
  const int r = t >> 4;
  const int cq = (t & 15) * 4;
  float acc[2][4] = {};
  for (int kc = 0; kc < FIN; kc += 64) {
    __syncthreads();
    {
      const int rr = t >> 4, cc = (t & 15) * 4;
      *(float4*)&xs[rr][cc] = *(const float4*)(x + (size_t)(r0 + rr) * FIN + kc + cc);
    }
#pragma unroll
    for (int i = 0; i < 8; ++i) {
      const int off = i * 1024 + t * 4;
      const int wr = off >> 7, wc = off & 127;
      *(float4*)&ws_[wr][wc] = *(const float4*)(w + (size_t)(kc + wr) * FOUT + wc);
    }
    __syncthreads();
    for (int kk = 0; kk < 64; ++kk) {
      const float xv = xs[r][kk];
#pragma unroll
      for (int g = 0; g < 2; ++g) {
        const float4 wv = *(const float4*)&ws_[kk][cq + 64 * g];
        acc[g][0] = fmaf(xv, wv.x, acc[g][0]);
        acc[g][1] = fmaf(xv, wv.y, acc[g][1]);
        acc[g][2] = fmaf(xv, wv.z, acc[g][2]);
        acc[g][3] = fmaf(xv, wv.w, acc[g][3]);
      }
    }
  }
  const int rg = r0 + r;
  float sp = 0.f, tp = 0.f;
#pragma unroll
  for (int g = 0; g < 2; ++g) {
#pragma unroll
    for (int e = 0; e < 4; ++e) {
      const int n = cq + 64 * g + e;
      const float v = acc[g][e];
      ht[r][n] = f2bf(v);
      sp = fmaf(v, av[n], sp);
      tp = fmaf(v, av[FOUT + n], tp);
    }
  }
#pragma unroll
  for (int d = 1; d < 16; d <<= 1) {
    sp += __shfl_xor(sp, d);
    tp += __shfl_xor(tp, d);
  }
  if ((t & 15) == 0) { sg[rg] = sp; tgo[rg] = tp; }
  __syncthreads();
  {
    const int half = blockIdx.x & 1;
    u16* dst = hb + (size_t)(blockIdx.x >> 1) * 4096;
    union { short8 v; u16 us[8]; } b1;
    const int i1 = t * 8;
    const int o1 = (i1 >> 8) * 512 + half * 256 + (i1 & 255);
    const int nblk = i1 >> 8;
#pragma unroll
    for (int q = 0; q < 8; ++q) {
      const int j = (i1 + q) & 255;
      b1.us[q] = ht[((j >> 7) & 1) * 8 + (j & 7)][nblk * 16 + ((j >> 3) & 15)];
    }
    *(short8*)(dst + o1) = b1.v;
  }
}

// K2: FUSED mask + att-writer on the r16 k_maskA skeleton (2 rows/wave,
// 1024 thr, 100% occupancy — the shape measured at ~45us for phase 1).
// Phase 1: dual-row NT adj stream -> nibbles to LDS + denominators.
// Write-out: maskT only (PV); no maskR buffer at all.
// Phase 2: each wave writes its 2 att rows straight from LDS bits
// (dense 1KB NT stores). Block-level pipelining overlaps late blocks'
// adj reads with early blocks' att writes.
__global__ __launch_bounds__(1024, 2) void k_fms2(const int* __restrict__ adj,
                                                  const float* __restrict__ sg,
                                                  const float* __restrict__ tg,
                                                  u32* __restrict__ maskT,
                                                  float* __restrict__ c2g,
                                                  float* __restrict__ att) {
  __shared__ u32 mlds[32][257];
  const int tid = threadIdx.x;
  const int w = tid >> 6, lane = tid & 63;
  const int r0 = blockIdx.x << 5;          // 32 rows/block
  const int rA = r0 + 2 * w, rB = rA + 1;
  const float sA = sg[rA], sB = sg[rB];
  const i32x4* apA = (const i32x4*)(adj + (size_t)rA * NN);
  const i32x4* apB = (const i32x4*)(adj + (size_t)rB * NN);
  float sumA = 0.f, sumB = 0.f;
#pragma unroll 2
  for (int it = 0; it < 32; ++it) {
    const i32x4 a0 = __builtin_nontemporal_load(apA + it * 64 + lane);
    const i32x4 a1 = __builtin_nontemporal_load(apB + it * 64 + lane);
    const float4 tv = *(const float4*)(tg + it * 256 + lane * 4);
    u32 nib0 = 0u, nib1 = 0u;
    {
      float e, p, sm = 0.f;
      e = sA + tv.x; e = fmaxf(e, NEG * e); p = EXP2(e * L2E); sm += (a0.x > 0) ? p : 0.f; nib0 |= (a0.x > 0) ? 1u : 0u;
      e = sA + tv.y; e = fmaxf(e, NEG * e); p = EXP2(e * L2E); sm += (a0.y > 0) ? p : 0.f; nib0 |= (a0.y > 0) ? 2u : 0u;
      e = sA + tv.z; e = fmaxf(e, NEG * e); p = EXP2(e * L2E); sm += (a0.z > 0) ? p : 0.f; nib0 |= (a0.z > 0) ? 4u : 0u;
      e = sA + tv.w; e = fmaxf(e, NEG * e); p = EXP2(e * L2E); sm += (a0.w > 0) ? p : 0.f; nib0 |= (a0.w > 0) ? 8u : 0u;
      sumA += sm;
    }
    {
      float e, p, sm = 0.f;
      e = sB + tv.x; e = fmaxf(e, NEG * e); p = EXP2(e * L2E); sm += (a1.x > 0) ? p : 0.f; nib1 |= (a1.x > 0) ? 1u : 0u;
      e = sB + tv.y; e = fmaxf(e, NEG * e); p = EXP2(e * L2E); sm += (a1.y > 0) ? p : 0.f; nib1 |= (a1.y > 0) ? 2u : 0u;
      e = sB + tv.z; e = fmaxf(e, NEG * e); p = EXP2(e * L2E); sm += (a1.z > 0) ? p : 0.f; nib1 |= (a1.z > 0) ? 4u : 0u;
      e = sB + tv.w; e = fmaxf(e, NEG * e); p = EXP2(e * L2E); sm += (a1.w > 0) ? p : 0.f; nib1 |= (a1.w > 0) ? 8u : 0u;
      sumB += sm;
    }
    u32 v0 = nib0;
    v0 |= __shfl_xor(v0, 1) << 4;
    v0 |= __shfl_xor(v0, 2) << 8;
    v0 |= __shfl_xor(v0, 4) << 16;
    u32 v1 = nib1;
    v1 |= __shfl_xor(v1, 1) << 4;
    v1 |= __shfl_xor(v1, 2) << 8;
    v1 |= __shfl_xor(v1, 4) << 16;
    if ((lane & 7) == 0) {
      mlds[2 * w][it * 8 + (lane >> 3)] = v0;
      mlds[2 * w + 1][it * 8 + (lane >> 3)] = v1;
    }
  }
#pragma unroll
  for (int d = 1; d < 64; d <<= 1) {
    sumA += __shfl_xor(sumA, d);
    sumB += __shfl_xor(sumB, d);
  }
  const float c2A = -LOG2(sumA), c2B = -LOG2(sumB);
  if (lane == 0) {
    c2g[rA] = c2A;
    c2g[rB] = c2B;
  }
  __syncthreads();
  // maskT write-out: 8192 words, 128B-contiguous chunks (32 rows).
  for (int idx = tid; idx < 8192; idx += 1024) {
    const int wi = idx >> 5, rr = idx & 31;
    maskT[(size_t)wi * NN + r0 + rr] = mlds[rr][wi];
  }
  // Phase 2: write att rows rA, rB from LDS bits (broadcast reads, free).
  float* aA = att + (size_t)rA * NN;
  float* aB = att + (size_t)rB * NN;
  const u32 sh = (lane & 7) * 4;
#pragma unroll 2
  for (int it = 0; it < 32; ++it) {
    const int jo = it * 256 + lane * 4;
    const float4 tv = *(const float4*)(tg + jo);
    const int wi = it * 8 + (lane >> 3);
    const u32 nibA = (mlds[2 * w][wi] >> sh) & 0xfu;
    const u32 nibB = (mlds[2 * w + 1][wi] >> sh) & 0xfu;
    float e0 = sA + tv.x; e0 = fmaxf(e0, NEG * e0);
    float e1 = sA + tv.y; e1 = fmaxf(e1, NEG * e1);
    float e2 = sA + tv.z; e2 = fmaxf(e2, NEG * e2);
    float e3 = sA + tv.w; e3 = fmaxf(e3, NEG * e3);
    f32x4 oA;
    oA.x = (nibA & 1u) ? EXP2(fmaf(e0, L2E, c2A)) : 0.f;
    oA.y = (nibA & 2u) ? EXP2(fmaf(e1, L2E, c2A)) : 0.f;
    oA.z = (nibA & 4u) ? EXP2(fmaf(e2, L2E, c2A)) : 0.f;
    oA.w = (nibA & 8u) ? EXP2(fmaf(e3, L2E, c2A)) : 0.f;
    __builtin_nontemporal_store(oA, (f32x4*)(aA + jo));
    e0 = sB + tv.x; e0 = fmaxf(e0, NEG * e0);
    e1 = sB + tv.y; e1 = fmaxf(e1, NEG * e1);
    e2 = sB + tv.z; e2 = fmaxf(e2, NEG * e2);
    e3 = sB + tv.w; e3 = fmaxf(e3, NEG * e3);
    f32x4 oB;
    oB.x = (nibB & 1u) ? EXP2(fmaf(e0, L2E, c2B)) : 0.f;
    oB.y = (nibB & 2u) ? EXP2(fmaf(e1, L2E, c2B)) : 0.f;
    oB.z = (nibB & 4u) ? EXP2(fmaf(e2, L2E, c2B)) : 0.f;
    oB.w = (nibB & 8u) ? EXP2(fmaf(e3, L2E, c2B)) : 0.f;
    __builtin_nontemporal_store(oB, (f32x4*)(aB + jo));
  }
}

// K3: PV — h' partials via bitmask-recomputed P (A-fragment order, no
// transpose), coalesced maskT reads, deterministic per-kt slices.
__global__ __launch_bounds__(512, 2) void k_pv(const float* __restrict__ sg,
                                               const float* __restrict__ tg,
                                               const float* __restrict__ c2g,
                                               const u32* __restrict__ maskT,
                                               const u16* __restrict__ hb,
                                               float* __restrict__ part) {
  const int tid = threadIdx.x;
  const int w = tid >> 6, lane = tid & 63;
  const int mt = blockIdx.x >> 3, kt = blockIdx.x & 7;
  const int wr = w >> 1, ch = w & 1;
  const int wrow = mt * 128 + wr * 32;
  const int arow = lane & 15, kg = lane >> 4;
  const int rowA = wrow + arow, rowB = wrow + 16 + arow;
  const float sA = sg[rowA], cA = c2g[rowA];
  const float sB = sg[rowB], cB = c2g[rowB];
  f32x4 acc0[4], acc1[4];
#pragma unroll
  for (int j = 0; j < 4; ++j) {
    acc0[j] = (f32x4){0.f, 0.f, 0.f, 0.f};
    acc1[j] = (f32x4){0.f, 0.f, 0.f, 0.f};
  }
  const int kg8 = kg * 8;
#pragma unroll 2
  for (int step = 0; step < 32; ++step) {
    const int kgrp = kt * 32 + step;
    const int k0 = kgrp * 32;
    const u32 wdA = maskT[(size_t)kgrp * NN + rowA];
    const u32 wdB = maskT[(size_t)kgrp * NN + rowB];
    const u32 bA = (wdA >> kg8) & 0xffu;
    const u32 bB = (wdB >> kg8) & 0xffu;
    const float4 t0 = *(const float4*)(tg + k0 + kg8);
    const float4 t1 = *(const float4*)(tg + k0 + kg8 + 4);
    const float tv[8] = {t0.x, t0.y, t0.z, t0.w, t1.x, t1.y, t1.z, t1.w};
    union { short8 s8; u32 u[4]; } afA, afB;
    {
      float p[8];
#pragma unroll
      for (int e = 0; e < 8; ++e) {
        float ev = sA + tv[e];
        ev = fmaxf(ev, NEG * ev);
        p[e] = ((bA >> e) & 1u) ? EXP2(fmaf(ev, L2E, cA)) : 0.f;
      }
#pragma unroll
      for (int h2 = 0; h2 < 4; ++h2)
        afA.u[h2] = (u32)f2bf(p[2 * h2]) | ((u32)f2bf(p[2 * h2 + 1]) << 16);
    }
    {
      float p[8];
#pragma unroll
      for (int e = 0; e < 8; ++e) {
        float ev = sB + tv[e];
        ev = fmaxf(ev, NEG * ev);
        p[e] = ((bB >> e) & 1u) ? EXP2(fmaf(ev, L2E, cB)) : 0.f;
      }
#pragma unroll
      for (int h2 = 0; h2 < 4; ++h2)
        afB.u[h2] = (u32)f2bf(p[2 * h2]) | ((u32)f2bf(p[2 * h2 + 1]) << 16);
    }
    const u16* base = hb + (size_t)kgrp * 4096 + ch * 2048 + lane * 8;
#pragma unroll
    for (int j = 0; j < 4; ++j) {
      const short8 bf = *(const short8*)(base + j * 512);
      acc0[j] = __builtin_amdgcn_mfma_f32_16x16x32_bf16(afA.s8, bf, acc0[j], 0, 0, 0);
      acc1[j] = __builtin_amdgcn_mfma_f32_16x16x32_bf16(afB.s8, bf, acc1[j], 0, 0, 0);
    }
  }
  float* pslice = part + (size_t)kt * (NN * FOUT);
#pragma unroll
  for (int j = 0; j < 4; ++j) {
    const int col = (ch * 4 + j) * 16 + arow;
#pragma unroll
    for (int q = 0; q < 4; ++q) {
      pslice[(size_t)(wrow + kg * 4 + q) * FOUT + col] = acc0[j][q];
      pslice[(size_t)(wrow + 16 + kg * 4 + q) * FOUT + col] = acc1[j][q];
    }
  }
}

// K4: hp = sum over 8 partial slices.
__global__ __launch_bounds__(256) void k_red(const float* __restrict__ part,
                                             float* __restrict__ hp) {
  const int i = (blockIdx.x * 256 + threadIdx.x) * 4;
  f32x4 s = (f32x4){0.f, 0.f, 0.f, 0.f};
#pragma unroll
  for (int kt = 0; kt < 8; ++kt)
    s += *(const f32x4*)(part + (size_t)kt * (NN * FOUT) + i);
  *(f32x4*)(hp + i) = s;
}

extern "C" void kernel_launch(void* const* d_in, const int* in_sizes, int n_in,
                              void* d_out, int out_size, void* d_ws, size_t ws_size,
                              hipStream_t stream) {
  const float* x = (const float*)d_in[0];
  const int* adj = (const int*)d_in[1];
  const float* w = (const float*)d_in[2];
  const float* a = (const float*)d_in[3];
  float* out = (float*)d_out;
  float* att = out;
  float* hp = out + (size_t)NN * NN;
  u16* hb = (u16*)d_ws;                                            // [0, 2MB)
  float* s = (float*)((char*)d_ws + (size_t)2 * 1024 * 1024);
  float* t = s + NN;
  float* c2 = t + NN;
  u32* maskT = (u32*)((char*)d_ws + (size_t)4 * 1024 * 1024);      // [4, 12MB)
  float* part = (float*)((char*)d_ws + (size_t)12 * 1024 * 1024);  // [12, 44MB)

  k_h<<<512, 256, 0, stream>>>(x, w, a, hb, s, t);
  k_fms2<<<256, 1024, 0, stream>>>(adj, s, t, maskT, c2, att);
  k_pv<<<512, 512, 0, stream>>>(s, t, c2, maskT, hb, part);
  k_red<<<1024, 256, 0, stream>>>(part, hp);
}

// Round 19
// 182.380 us; speedup vs baseline: 1.0408x; 1.0408x over previous
//
#include <hip/hip_runtime.h>
#include <hip/hip_bf16.h>

typedef unsigned short u16;
typedef unsigned int u32;
typedef __attribute__((ext_vector_type(8))) short short8;
typedef __attribute__((ext_vector_type(4))) float f32x4;
typedef __attribute__((ext_vector_type(4))) int i32x4;

#define NN 8192
#define FIN 512
#define FOUT 128
#define NEG 0.2f
#define L2E 1.44269504088896340736f
#define EXP2(x) __builtin_amdgcn_exp2f(x)
#define LOG2(x) __builtin_amdgcn_logf(x)

__device__ __forceinline__ u16 f2bf(float f) {
  u32 u = __builtin_bit_cast(u32, f);
  u32 r = (u + 0x7fffu + ((u >> 16) & 1u)) >> 16;
  return (u16)r;
}

// K1: h = x @ w. 16-row tiles -> 512 blocks (2/CU, 8 waves/CU). Emits s,t
// scores and hb in MFMA-native coalesced layout:
// hb[kgrp][nblk][kg][nlo][e] = bf16(h[kgrp*32 + kg*8 + e][nblk*16 + nlo]).
__global__ __launch_bounds__(256) void k_h(const float* __restrict__ x,
                                           const float* __restrict__ w,
                                           const float* __restrict__ av,
                                           u16* __restrict__ hb,
                                           float* __restrict__ sg,
                                           float* __restrict__ tgo) {
  __shared__ float xs[16][68];
  __shared__ float ws_[64][128];
  __shared__ u16 ht[16][130];
  const int t = threadIdx.x;
  const int r0 = blockIdx.x * 16;
  const int r = t >> 4;
  const int cq = (t & 15) * 4;
  float acc[2][4] = {};
  for (int kc = 0; kc < FIN; kc += 64) {
    __syncthreads();
    {
      const int rr = t >> 4, cc = (t & 15) * 4;
      *(float4*)&xs[rr][cc] = *(const float4*)(x + (size_t)(r0 + rr) * FIN + kc + cc);
    }
#pragma unroll
    for (int i = 0; i < 8; ++i) {
      const int off = i * 1024 + t * 4;
      const int wr = off >> 7, wc = off & 127;
      *(float4*)&ws_[wr][wc] = *(const float4*)(w + (size_t)(kc + wr) * FOUT + wc);
    }
    __syncthreads();
    for (int kk = 0; kk < 64; ++kk) {
      const float xv = xs[r][kk];
#pragma unroll
      for (int g = 0; g < 2; ++g) {
        const float4 wv = *(const float4*)&ws_[kk][cq + 64 * g];
        acc[g][0] = fmaf(xv, wv.x, acc[g][0]);
        acc[g][1] = fmaf(xv, wv.y, acc[g][1]);
        acc[g][2] = fmaf(xv, wv.z, acc[g][2]);
        acc[g][3] = fmaf(xv, wv.w, acc[g][3]);
      }
    }
  }
  const int rg = r0 + r;
  float sp = 0.f, tp = 0.f;
#pragma unroll
  for (int g = 0; g < 2; ++g) {
#pragma unroll
    for (int e = 0; e < 4; ++e) {
      const int n = cq + 64 * g + e;
      const float v = acc[g][e];
      ht[r][n] = f2bf(v);
      sp = fmaf(v, av[n], sp);
      tp = fmaf(v, av[FOUT + n], tp);
    }
  }
#pragma unroll
  for (int d = 1; d < 16; d <<= 1) {
    sp += __shfl_xor(sp, d);
    tp += __shfl_xor(tp, d);
  }
  if ((t & 15) == 0) { sg[rg] = sp; tgo[rg] = tp; }
  __syncthreads();
  {
    const int half = blockIdx.x & 1;
    u16* dst = hb + (size_t)(blockIdx.x >> 1) * 4096;
    union { short8 v; u16 us[8]; } b1;
    const int i1 = t * 8;
    const int o1 = (i1 >> 8) * 512 + half * 256 + (i1 & 255);
    const int nblk = i1 >> 8;
#pragma unroll
    for (int q = 0; q < 8; ++q) {
      const int j = (i1 + q) & 255;
      b1.us[q] = ht[((j >> 7) & 1) * 8 + (j & 7)][nblk * 16 + ((j >> 3) & 15)];
    }
    *(short8*)(dst + o1) = b1.v;
  }
}

// K2: stream adj ONCE. 2 rows per wave (2x in-flight loads for the
// latency-bound stream; t-loads shared). 1024 thr, (1024,2) -> 100% occ.
// Emits both mask layouts + c2 = -log2(sum).
__global__ __launch_bounds__(1024, 2) void k_maskA(const int* __restrict__ adj,
                                                   const float* __restrict__ sg,
                                                   const float* __restrict__ tg,
                                                   u32* __restrict__ maskR,
                                                   u32* __restrict__ maskT,
                                                   float* __restrict__ c2g) {
  __shared__ u32 mlds[32][257];
  const int tid = threadIdx.x;
  const int w = tid >> 6, lane = tid & 63;
  const int r0 = blockIdx.x << 5;          // 32 rows/block
  const int rA = r0 + 2 * w, rB = rA + 1;
  const float sA = sg[rA], sB = sg[rB];
  const i32x4* apA = (const i32x4*)(adj + (size_t)rA * NN);
  const i32x4* apB = (const i32x4*)(adj + (size_t)rB * NN);
  float sumA = 0.f, sumB = 0.f;
#pragma unroll 2
  for (int it = 0; it < 32; ++it) {
    const i32x4 a0 = __builtin_nontemporal_load(apA + it * 64 + lane);
    const i32x4 a1 = __builtin_nontemporal_load(apB + it * 64 + lane);
    const float4 tv = *(const float4*)(tg + it * 256 + lane * 4);
    u32 nib0 = 0u, nib1 = 0u;
    {
      float e, p, sm = 0.f;
      e = sA + tv.x; e = fmaxf(e, NEG * e); p = EXP2(e * L2E); sm += (a0.x > 0) ? p : 0.f; nib0 |= (a0.x > 0) ? 1u : 0u;
      e = sA + tv.y; e = fmaxf(e, NEG * e); p = EXP2(e * L2E); sm += (a0.y > 0) ? p : 0.f; nib0 |= (a0.y > 0) ? 2u : 0u;
      e = sA + tv.z; e = fmaxf(e, NEG * e); p = EXP2(e * L2E); sm += (a0.z > 0) ? p : 0.f; nib0 |= (a0.z > 0) ? 4u : 0u;
      e = sA + tv.w; e = fmaxf(e, NEG * e); p = EXP2(e * L2E); sm += (a0.w > 0) ? p : 0.f; nib0 |= (a0.w > 0) ? 8u : 0u;
      sumA += sm;
    }
    {
      float e, p, sm = 0.f;
      e = sB + tv.x; e = fmaxf(e, NEG * e); p = EXP2(e * L2E); sm += (a1.x > 0) ? p : 0.f; nib1 |= (a1.x > 0) ? 1u : 0u;
      e = sB + tv.y; e = fmaxf(e, NEG * e); p = EXP2(e * L2E); sm += (a1.y > 0) ? p : 0.f; nib1 |= (a1.y > 0) ? 2u : 0u;
      e = sB + tv.z; e = fmaxf(e, NEG * e); p = EXP2(e * L2E); sm += (a1.z > 0) ? p : 0.f; nib1 |= (a1.z > 0) ? 4u : 0u;
      e = sB + tv.w; e = fmaxf(e, NEG * e); p = EXP2(e * L2E); sm += (a1.w > 0) ? p : 0.f; nib1 |= (a1.w > 0) ? 8u : 0u;
      sumB += sm;
    }
    u32 v0 = nib0;
    v0 |= __shfl_xor(v0, 1) << 4;
    v0 |= __shfl_xor(v0, 2) << 8;
    v0 |= __shfl_xor(v0, 4) << 16;
    u32 v1 = nib1;
    v1 |= __shfl_xor(v1, 1) << 4;
    v1 |= __shfl_xor(v1, 2) << 8;
    v1 |= __shfl_xor(v1, 4) << 16;
    if ((lane & 7) == 0) {
      mlds[2 * w][it * 8 + (lane >> 3)] = v0;
      mlds[2 * w + 1][it * 8 + (lane >> 3)] = v1;
    }
  }
#pragma unroll
  for (int d = 1; d < 64; d <<= 1) {
    sumA += __shfl_xor(sumA, d);
    sumB += __shfl_xor(sumB, d);
  }
  if (lane == 0) {
    c2g[rA] = -LOG2(sumA);
    c2g[rB] = -LOG2(sumB);
  }
  __syncthreads();
  for (int idx = tid; idx < 8192; idx += 1024) {
    const int wi = idx >> 5, rr = idx & 31;
    const u32 v = mlds[rr][wi];
    maskR[(size_t)(r0 + rr) * 256 + wi] = v;
    maskT[(size_t)wi * NN + r0 + rr] = v;
  }
}

// K3: fused consumer. Blocks [0,256): PV role with kt=4 (2048-K slices, 64
// steps, halved partial traffic); blocks [256,2304): SOFT role (att writer,
// dense 1KB NT stores). Zero LDS, zero barriers in both roles.
__global__ __launch_bounds__(512, 4) void k_spv(const float* __restrict__ sg,
                                                const float* __restrict__ tg,
                                                const float* __restrict__ c2g,
                                                const u32* __restrict__ maskR,
                                                const u32* __restrict__ maskT,
                                                const u16* __restrict__ hb,
                                                float* __restrict__ att,
                                                float* __restrict__ part) {
  const int tid = threadIdx.x;
  const int w = tid >> 6, lane = tid & 63;
  if (blockIdx.x < 256) {
    // ---- PV ----
    const int mt = blockIdx.x >> 2, kt = blockIdx.x & 3;
    const int wr = w >> 1, ch = w & 1;
    const int wrow = mt * 128 + wr * 32;
    const int arow = lane & 15, kg = lane >> 4;
    const int rowA = wrow + arow, rowB = wrow + 16 + arow;
    const float sA = sg[rowA], cA = c2g[rowA];
    const float sB = sg[rowB], cB = c2g[rowB];
    f32x4 acc0[4], acc1[4];
#pragma unroll
    for (int j = 0; j < 4; ++j) {
      acc0[j] = (f32x4){0.f, 0.f, 0.f, 0.f};
      acc1[j] = (f32x4){0.f, 0.f, 0.f, 0.f};
    }
    const int kg8 = kg * 8;
#pragma unroll 2
    for (int step = 0; step < 64; ++step) {
      const int kgrp = kt * 64 + step;
      const int k0 = kgrp * 32;
      const u32 wdA = maskT[(size_t)kgrp * NN + rowA];      // 64B-coalesced
      const u32 wdB = maskT[(size_t)kgrp * NN + rowB];
      const u32 bA = (wdA >> kg8) & 0xffu;
      const u32 bB = (wdB >> kg8) & 0xffu;
      const float4 t0 = *(const float4*)(tg + k0 + kg8);
      const float4 t1 = *(const float4*)(tg + k0 + kg8 + 4);
      const float tv[8] = {t0.x, t0.y, t0.z, t0.w, t1.x, t1.y, t1.z, t1.w};
      union { short8 s8; u32 u[4]; } afA, afB;
      {
        float p[8];
#pragma unroll
        for (int e = 0; e < 8; ++e) {
          float ev = sA + tv[e];
          ev = fmaxf(ev, NEG * ev);
          p[e] = ((bA >> e) & 1u) ? EXP2(fmaf(ev, L2E, cA)) : 0.f;
        }
#pragma unroll
        for (int h2 = 0; h2 < 4; ++h2)
          afA.u[h2] = (u32)f2bf(p[2 * h2]) | ((u32)f2bf(p[2 * h2 + 1]) << 16);
      }
      {
        float p[8];
#pragma unroll
        for (int e = 0; e < 8; ++e) {
          float ev = sB + tv[e];
          ev = fmaxf(ev, NEG * ev);
          p[e] = ((bB >> e) & 1u) ? EXP2(fmaf(ev, L2E, cB)) : 0.f;
        }
#pragma unroll
        for (int h2 = 0; h2 < 4; ++h2)
          afB.u[h2] = (u32)f2bf(p[2 * h2]) | ((u32)f2bf(p[2 * h2 + 1]) << 16);
      }
      const u16* base = hb + (size_t)kgrp * 4096 + ch * 2048 + lane * 8;
#pragma unroll
      for (int j = 0; j < 4; ++j) {
        const short8 bf = *(const short8*)(base + j * 512);
        acc0[j] = __builtin_amdgcn_mfma_f32_16x16x32_bf16(afA.s8, bf, acc0[j], 0, 0, 0);
        acc1[j] = __builtin_amdgcn_mfma_f32_16x16x32_bf16(afB.s8, bf, acc1[j], 0, 0, 0);
      }
    }
    float* pslice = part + (size_t)kt * (NN * FOUT);
#pragma unroll
    for (int j = 0; j < 4; ++j) {
      const int col = (ch * 4 + j) * 16 + arow;
#pragma unroll
      for (int q = 0; q < 4; ++q) {
        pslice[(size_t)(wrow + kg * 4 + q) * FOUT + col] = acc0[j][q];
        pslice[(size_t)(wrow + 16 + kg * 4 + q) * FOUT + col] = acc1[j][q];
      }
    }
  } else {
    // ---- SOFT ----
    const int sb = blockIdx.x - 256;           // 4 rows each
    const int row = sb * 4 + (w >> 1);
    const int half = w & 1;
    const float sv = sg[row];
    const float c2 = c2g[row];
    const u32* mrow = maskR + (size_t)row * 256 + half * 128;
    const float* tbase = tg + half * 4096;
    float* abase = att + (size_t)row * NN + half * 4096;
    const u32 sh = (lane & 7) * 4;
#pragma unroll 4
    for (int it = 0; it < 16; ++it) {
      const int jo = it * 256 + lane * 4;
      const u32 wd = mrow[it * 8 + (lane >> 3)];
      const u32 nib = (wd >> sh) & 0xfu;
      const float4 tv = *(const float4*)(tbase + jo);
      float e0 = sv + tv.x; e0 = fmaxf(e0, NEG * e0);
      float e1 = sv + tv.y; e1 = fmaxf(e1, NEG * e1);
      float e2 = sv + tv.z; e2 = fmaxf(e2, NEG * e2);
      float e3 = sv + tv.w; e3 = fmaxf(e3, NEG * e3);
      f32x4 o;
      o.x = (nib & 1u) ? EXP2(fmaf(e0, L2E, c2)) : 0.f;
      o.y = (nib & 2u) ? EXP2(fmaf(e1, L2E, c2)) : 0.f;
      o.z = (nib & 4u) ? EXP2(fmaf(e2, L2E, c2)) : 0.f;
      o.w = (nib & 8u) ? EXP2(fmaf(e3, L2E, c2)) : 0.f;
      __builtin_nontemporal_store(o, (f32x4*)(abase + jo));
    }
  }
}

// K4: hp = sum over 4 partial slices.
__global__ __launch_bounds__(256) void k_red(const float* __restrict__ part,
                                             float* __restrict__ hp) {
  const int i = (blockIdx.x * 256 + threadIdx.x) * 4;
  f32x4 s = (f32x4){0.f, 0.f, 0.f, 0.f};
#pragma unroll
  for (int kt = 0; kt < 4; ++kt)
    s += *(const f32x4*)(part + (size_t)kt * (NN * FOUT) + i);
  *(f32x4*)(hp + i) = s;
}

extern "C" void kernel_launch(void* const* d_in, const int* in_sizes, int n_in,
                              void* d_out, int out_size, void* d_ws, size_t ws_size,
                              hipStream_t stream) {
  const float* x = (const float*)d_in[0];
  const int* adj = (const int*)d_in[1];
  const float* w = (const float*)d_in[2];
  const float* a = (const float*)d_in[3];
  float* out = (float*)d_out;
  float* att = out;
  float* hp = out + (size_t)NN * NN;
  u16* hb = (u16*)d_ws;                                            // [0, 2MB)
  float* s = (float*)((char*)d_ws + (size_t)2 * 1024 * 1024);
  float* t = s + NN;
  float* c2 = t + NN;
  u32* maskR = (u32*)((char*)d_ws + (size_t)4 * 1024 * 1024);      // [4, 12MB)
  u32* maskT = (u32*)((char*)d_ws + (size_t)12 * 1024 * 1024);     // [12, 20MB)
  float* part = (float*)((char*)d_ws + (size_t)20 * 1024 * 1024);  // [20, 36MB)

  k_h<<<512, 256, 0, stream>>>(x, w, a, hb, s, t);
  k_maskA<<<256, 1024, 0, stream>>>(adj, s, t, maskR, maskT, c2);
  k_spv<<<2304, 512, 0, stream>>>(s, t, c2, maskR, maskT, hb, att, part);
  k_red<<<1024, 256, 0, stream>>>(part, hp);
}

// Round 20
// 172.881 us; speedup vs baseline: 1.0979x; 1.0549x over previous
//
#include <hip/hip_runtime.h>
#include <hip/hip_bf16.h>

typedef unsigned short u16;
typedef unsigned int u32;
typedef __attribute__((ext_vector_type(8))) short short8;
typedef __attribute__((ext_vector_type(4))) float f32x4;
typedef __attribute__((ext_vector_type(4))) int i32x4;

#define NN 8192
#define FIN 512
#define FOUT 128
#define NEG 0.2f
#define L2E 1.44269504088896340736f
#define EXP2(x) __builtin_amdgcn_exp2f(x)
#define LOG2(x) __builtin_amdgcn_logf(x)

__device__ __forceinline__ u16 f2bf(float f) {
  u32 u = __builtin_bit_cast(u32, f);
  u32 r = (u + 0x7fffu + ((u >> 16) & 1u)) >> 16;
  return (u16)r;
}

// K1: h = x @ w. 16-row tiles -> 512 blocks (2/CU, 8 waves/CU). Emits s,t
// scores and hb in MFMA-native coalesced layout:
// hb[kgrp][nblk][kg][nlo][e] = bf16(h[kgrp*32 + kg*8 + e][nblk*16 + nlo]).
__global__ __launch_bounds__(256) void k_h(const float* __restrict__ x,
                                           const float* __restrict__ w,
                                           const float* __restrict__ av,
                                           u16* __restrict__ hb,
                                           float* __restrict__ sg,
                                           float* __restrict__ tgo) {
  __shared__ float xs[16][68];
  __shared__ float ws_[64][128];
  __shared__ u16 ht[16][130];
  const int t = threadIdx.x;
  const int r0 = blockIdx.x * 16;
  const int r = t >> 4;
  const int cq = (t & 15) * 4;
  float acc[2][4] = {};
  for (int kc = 0; kc < FIN; kc += 64) {
    __syncthreads();
    {
      const int rr = t >> 4, cc = (t & 15) * 4;
      *(float4*)&xs[rr][cc] = *(const float4*)(x + (size_t)(r0 + rr) * FIN + kc + cc);
    }
#pragma unroll
    for (int i = 0; i < 8; ++i) {
      const int off = i * 1024 + t * 4;
      const int wr = off >> 7, wc = off & 127;
      *(float4*)&ws_[wr][wc] = *(const float4*)(w + (size_t)(kc + wr) * FOUT + wc);
    }
    __syncthreads();
    for (int kk = 0; kk < 64; ++kk) {
      const float xv = xs[r][kk];
#pragma unroll
      for (int g = 0; g < 2; ++g) {
        const float4 wv = *(const float4*)&ws_[kk][cq + 64 * g];
        acc[g][0] = fmaf(xv, wv.x, acc[g][0]);
        acc[g][1] = fmaf(xv, wv.y, acc[g][1]);
        acc[g][2] = fmaf(xv, wv.z, acc[g][2]);
        acc[g][3] = fmaf(xv, wv.w, acc[g][3]);
      }
    }
  }
  const int rg = r0 + r;
  float sp = 0.f, tp = 0.f;
#pragma unroll
  for (int g = 0; g < 2; ++g) {
#pragma unroll
    for (int e = 0; e < 4; ++e) {
      const int n = cq + 64 * g + e;
      const float v = acc[g][e];
      ht[r][n] = f2bf(v);
      sp = fmaf(v, av[n], sp);
      tp = fmaf(v, av[FOUT + n], tp);
    }
  }
#pragma unroll
  for (int d = 1; d < 16; d <<= 1) {
    sp += __shfl_xor(sp, d);
    tp += __shfl_xor(tp, d);
  }
  if ((t & 15) == 0) { sg[rg] = sp; tgo[rg] = tp; }
  __syncthreads();
  {
    const int half = blockIdx.x & 1;
    u16* dst = hb + (size_t)(blockIdx.x >> 1) * 4096;
    union { short8 v; u16 us[8]; } b1;
    const int i1 = t * 8;
    const int o1 = (i1 >> 8) * 512 + half * 256 + (i1 & 255);
    const int nblk = i1 >> 8;
#pragma unroll
    for (int q = 0; q < 8; ++q) {
      const int j = (i1 + q) & 255;
      b1.us[q] = ht[((j >> 7) & 1) * 8 + (j & 7)][nblk * 16 + ((j >> 3) & 15)];
    }
    *(short8*)(dst + o1) = b1.v;
  }
}

// K2: stream adj ONCE. 2 rows per wave (2x in-flight loads for the
// latency-bound stream; t-loads shared). 1024 thr, (1024,2) -> 100% occ.
// Emits both mask layouts + c2 = -log2(sum).
__global__ __launch_bounds__(1024, 2) void k_maskA(const int* __restrict__ adj,
                                                   const float* __restrict__ sg,
                                                   const float* __restrict__ tg,
                                                   u32* __restrict__ maskR,
                                                   u32* __restrict__ maskT,
                                                   float* __restrict__ c2g) {
  __shared__ u32 mlds[32][257];
  const int tid = threadIdx.x;
  const int w = tid >> 6, lane = tid & 63;
  const int r0 = blockIdx.x << 5;          // 32 rows/block
  const int rA = r0 + 2 * w, rB = rA + 1;
  const float sA = sg[rA], sB = sg[rB];
  const i32x4* apA = (const i32x4*)(adj + (size_t)rA * NN);
  const i32x4* apB = (const i32x4*)(adj + (size_t)rB * NN);
  float sumA = 0.f, sumB = 0.f;
#pragma unroll 2
  for (int it = 0; it < 32; ++it) {
    const i32x4 a0 = __builtin_nontemporal_load(apA + it * 64 + lane);
    const i32x4 a1 = __builtin_nontemporal_load(apB + it * 64 + lane);
    const float4 tv = *(const float4*)(tg + it * 256 + lane * 4);
    u32 nib0 = 0u, nib1 = 0u;
    {
      float e, p, sm = 0.f;
      e = sA + tv.x; e = fmaxf(e, NEG * e); p = EXP2(e * L2E); sm += (a0.x > 0) ? p : 0.f; nib0 |= (a0.x > 0) ? 1u : 0u;
      e = sA + tv.y; e = fmaxf(e, NEG * e); p = EXP2(e * L2E); sm += (a0.y > 0) ? p : 0.f; nib0 |= (a0.y > 0) ? 2u : 0u;
      e = sA + tv.z; e = fmaxf(e, NEG * e); p = EXP2(e * L2E); sm += (a0.z > 0) ? p : 0.f; nib0 |= (a0.z > 0) ? 4u : 0u;
      e = sA + tv.w; e = fmaxf(e, NEG * e); p = EXP2(e * L2E); sm += (a0.w > 0) ? p : 0.f; nib0 |= (a0.w > 0) ? 8u : 0u;
      sumA += sm;
    }
    {
      float e, p, sm = 0.f;
      e = sB + tv.x; e = fmaxf(e, NEG * e); p = EXP2(e * L2E); sm += (a1.x > 0) ? p : 0.f; nib1 |= (a1.x > 0) ? 1u : 0u;
      e = sB + tv.y; e = fmaxf(e, NEG * e); p = EXP2(e * L2E); sm += (a1.y > 0) ? p : 0.f; nib1 |= (a1.y > 0) ? 2u : 0u;
      e = sB + tv.z; e = fmaxf(e, NEG * e); p = EXP2(e * L2E); sm += (a1.z > 0) ? p : 0.f; nib1 |= (a1.z > 0) ? 4u : 0u;
      e = sB + tv.w; e = fmaxf(e, NEG * e); p = EXP2(e * L2E); sm += (a1.w > 0) ? p : 0.f; nib1 |= (a1.w > 0) ? 8u : 0u;
      sumB += sm;
    }
    u32 v0 = nib0;
    v0 |= __shfl_xor(v0, 1) << 4;
    v0 |= __shfl_xor(v0, 2) << 8;
    v0 |= __shfl_xor(v0, 4) << 16;
    u32 v1 = nib1;
    v1 |= __shfl_xor(v1, 1) << 4;
    v1 |= __shfl_xor(v1, 2) << 8;
    v1 |= __shfl_xor(v1, 4) << 16;
    if ((lane & 7) == 0) {
      mlds[2 * w][it * 8 + (lane >> 3)] = v0;
      mlds[2 * w + 1][it * 8 + (lane >> 3)] = v1;
    }
  }
#pragma unroll
  for (int d = 1; d < 64; d <<= 1) {
    sumA += __shfl_xor(sumA, d);
    sumB += __shfl_xor(sumB, d);
  }
  if (lane == 0) {
    c2g[rA] = -LOG2(sumA);
    c2g[rB] = -LOG2(sumB);
  }
  __syncthreads();
  for (int idx = tid; idx < 8192; idx += 1024) {
    const int wi = idx >> 5, rr = idx & 31;
    const u32 v = mlds[rr][wi];
    maskR[(size_t)(r0 + rr) * 256 + wi] = v;
    maskT[(size_t)wi * NN + r0 + rr] = v;
  }
}

// K3: fused consumer. Blocks [0,512): PV role (h' partials via bitmask-
// recomputed P, deterministic per-kt slices); blocks [512,2560): SOFT role
// (att writer, dense 1KB NT stores). Zero LDS, zero barriers in both roles.
__global__ __launch_bounds__(512, 4) void k_spv(const float* __restrict__ sg,
                                                const float* __restrict__ tg,
                                                const float* __restrict__ c2g,
                                                const u32* __restrict__ maskR,
                                                const u32* __restrict__ maskT,
                                                const u16* __restrict__ hb,
                                                float* __restrict__ att,
                                                float* __restrict__ part) {
  const int tid = threadIdx.x;
  const int w = tid >> 6, lane = tid & 63;
  if (blockIdx.x < 512) {
    // ---- PV ----
    const int mt = blockIdx.x >> 3, kt = blockIdx.x & 7;
    const int wr = w >> 1, ch = w & 1;
    const int wrow = mt * 128 + wr * 32;
    const int arow = lane & 15, kg = lane >> 4;
    const int rowA = wrow + arow, rowB = wrow + 16 + arow;
    const float sA = sg[rowA], cA = c2g[rowA];
    const float sB = sg[rowB], cB = c2g[rowB];
    f32x4 acc0[4], acc1[4];
#pragma unroll
    for (int j = 0; j < 4; ++j) {
      acc0[j] = (f32x4){0.f, 0.f, 0.f, 0.f};
      acc1[j] = (f32x4){0.f, 0.f, 0.f, 0.f};
    }
    const int kg8 = kg * 8;
#pragma unroll 2
    for (int step = 0; step < 32; ++step) {
      const int kgrp = kt * 32 + step;
      const int k0 = kgrp * 32;
      const u32 wdA = maskT[(size_t)kgrp * NN + rowA];      // 64B-coalesced
      const u32 wdB = maskT[(size_t)kgrp * NN + rowB];
      const u32 bA = (wdA >> kg8) & 0xffu;
      const u32 bB = (wdB >> kg8) & 0xffu;
      const float4 t0 = *(const float4*)(tg + k0 + kg8);
      const float4 t1 = *(const float4*)(tg + k0 + kg8 + 4);
      const float tv[8] = {t0.x, t0.y, t0.z, t0.w, t1.x, t1.y, t1.z, t1.w};
      union { short8 s8; u32 u[4]; } afA, afB;
      {
        float p[8];
#pragma unroll
        for (int e = 0; e < 8; ++e) {
          float ev = sA + tv[e];
          ev = fmaxf(ev, NEG * ev);
          p[e] = ((bA >> e) & 1u) ? EXP2(fmaf(ev, L2E, cA)) : 0.f;
        }
#pragma unroll
        for (int h2 = 0; h2 < 4; ++h2)
          afA.u[h2] = (u32)f2bf(p[2 * h2]) | ((u32)f2bf(p[2 * h2 + 1]) << 16);
      }
      {
        float p[8];
#pragma unroll
        for (int e = 0; e < 8; ++e) {
          float ev = sB + tv[e];
          ev = fmaxf(ev, NEG * ev);
          p[e] = ((bB >> e) & 1u) ? EXP2(fmaf(ev, L2E, cB)) : 0.f;
        }
#pragma unroll
        for (int h2 = 0; h2 < 4; ++h2)
          afB.u[h2] = (u32)f2bf(p[2 * h2]) | ((u32)f2bf(p[2 * h2 + 1]) << 16);
      }
      const u16* base = hb + (size_t)kgrp * 4096 + ch * 2048 + lane * 8;
#pragma unroll
      for (int j = 0; j < 4; ++j) {
        const short8 bf = *(const short8*)(base + j * 512);
        acc0[j] = __builtin_amdgcn_mfma_f32_16x16x32_bf16(afA.s8, bf, acc0[j], 0, 0, 0);
        acc1[j] = __builtin_amdgcn_mfma_f32_16x16x32_bf16(afB.s8, bf, acc1[j], 0, 0, 0);
      }
    }
    float* pslice = part + (size_t)kt * (NN * FOUT);
#pragma unroll
    for (int j = 0; j < 4; ++j) {
      const int col = (ch * 4 + j) * 16 + arow;
#pragma unroll
      for (int q = 0; q < 4; ++q) {
        pslice[(size_t)(wrow + kg * 4 + q) * FOUT + col] = acc0[j][q];
        pslice[(size_t)(wrow + 16 + kg * 4 + q) * FOUT + col] = acc1[j][q];
      }
    }
  } else {
    // ---- SOFT ----
    const int sb = blockIdx.x - 512;           // 4 rows each
    const int row = sb * 4 + (w >> 1);
    const int half = w & 1;
    const float sv = sg[row];
    const float c2 = c2g[row];
    const u32* mrow = maskR + (size_t)row * 256 + half * 128;
    const float* tbase = tg + half * 4096;
    float* abase = att + (size_t)row * NN + half * 4096;
    const u32 sh = (lane & 7) * 4;
#pragma unroll 4
    for (int it = 0; it < 16; ++it) {
      const int jo = it * 256 + lane * 4;
      const u32 wd = mrow[it * 8 + (lane >> 3)];
      const u32 nib = (wd >> sh) & 0xfu;
      const float4 tv = *(const float4*)(tbase + jo);
      float e0 = sv + tv.x; e0 = fmaxf(e0, NEG * e0);
      float e1 = sv + tv.y; e1 = fmaxf(e1, NEG * e1);
      float e2 = sv + tv.z; e2 = fmaxf(e2, NEG * e2);
      float e3 = sv + tv.w; e3 = fmaxf(e3, NEG * e3);
      f32x4 o;
      o.x = (nib & 1u) ? EXP2(fmaf(e0, L2E, c2)) : 0.f;
      o.y = (nib & 2u) ? EXP2(fmaf(e1, L2E, c2)) : 0.f;
      o.z = (nib & 4u) ? EXP2(fmaf(e2, L2E, c2)) : 0.f;
      o.w = (nib & 8u) ? EXP2(fmaf(e3, L2E, c2)) : 0.f;
      __builtin_nontemporal_store(o, (f32x4*)(abase + jo));
    }
  }
}

// K4: hp = sum over 8 partial slices.
__global__ __launch_bounds__(256) void k_red(const float* __restrict__ part,
                                             float* __restrict__ hp) {
  const int i = (blockIdx.x * 256 + threadIdx.x) * 4;
  f32x4 s = (f32x4){0.f, 0.f, 0.f, 0.f};
#pragma unroll
  for (int kt = 0; kt < 8; ++kt)
    s += *(const f32x4*)(part + (size_t)kt * (NN * FOUT) + i);
  *(f32x4*)(hp + i) = s;
}

extern "C" void kernel_launch(void* const* d_in, const int* in_sizes, int n_in,
                              void* d_out, int out_size, void* d_ws, size_t ws_size,
                              hipStream_t stream) {
  const float* x = (const float*)d_in[0];
  const int* adj = (const int*)d_in[1];
  const float* w = (const float*)d_in[2];
  const float* a = (const float*)d_in[3];
  float* out = (float*)d_out;
  float* att = out;
  float* hp = out + (size_t)NN * NN;
  u16* hb = (u16*)d_ws;                                            // [0, 2MB)
  float* s = (float*)((char*)d_ws + (size_t)2 * 1024 * 1024);
  float* t = s + NN;
  float* c2 = t + NN;
  u32* maskR = (u32*)((char*)d_ws + (size_t)4 * 1024 * 1024);      // [4, 12MB)
  u32* maskT = (u32*)((char*)d_ws + (size_t)12 * 1024 * 1024);     // [12, 20MB)
  float* part = (float*)((char*)d_ws + (size_t)20 * 1024 * 1024);  // [20, 36MB)

  k_h<<<512, 256, 0, stream>>>(x, w, a, hb, s, t);
  k_maskA<<<256, 1024, 0, stream>>>(adj, s, t, maskR, maskT, c2);
  k_spv<<<2560, 512, 0, stream>>>(s, t, c2, maskR, maskT, hb, att, part);
  k_red<<<1024, 256, 0, stream>>>(part, hp);
}